// Round 7
// baseline (306.333 us; speedup 1.0000x reference)
//
#include <hip/hip_runtime.h>

#define B_    4
#define C_    256
#define H_    64
#define W_    64
#define HW_   4096
#define NG_   32
#define CPG_  8
#define KK_   9
#define NOFF_ 18

typedef __attribute__((ext_vector_type(8))) short short8;
typedef __attribute__((ext_vector_type(4))) short short4v;
typedef __attribute__((ext_vector_type(4))) float floatx4;

static __device__ __forceinline__ short f2bf(float f) {
    union { float f; unsigned u; } v; v.f = f;
    unsigned r = v.u + 0x7fff + ((v.u >> 16) & 1);   // RNE
    return (short)(r >> 16);
}
static __device__ __forceinline__ float bf2f(short s) {
    union { unsigned u; float f; } v;
    v.u = ((unsigned)(unsigned short)s) << 16;
    return v.f;
}

// ---------------------------------------------------------------------------
// K0: prep — weight packs + gn1 stats + zero gn2-stats accumulators.
//   blocks 0..4607   : w1/w2 [O][C][3][3] -> fragment-major bf16
//   blocks 4608..4671: pw1/pw2 [18][C] -> A-frags padded to 32 rows
//   blocks 4672..4799: gn1 stats per (b,g) from x -> (mean, rsqrt)
//   block  4800      : zero gsum/gss
// ---------------------------------------------------------------------------
__global__ __launch_bounds__(256) void prep_kernel(
    const float* __restrict__ w1, const float* __restrict__ w2,
    const float* __restrict__ pw1, const float* __restrict__ pw2,
    const float* __restrict__ x,
    short* __restrict__ wp1, short* __restrict__ wp2,
    short* __restrict__ ppk1, short* __restrict__ ppk2,
    float2* __restrict__ stats1, float* __restrict__ gsum,
    float* __restrict__ gss)
{
    int blk = blockIdx.x;
    int t = threadIdx.x;
    if (blk < 4608) {
        const float* w = (blk < 2304) ? w1 : w2;
        short* wp = (blk < 2304) ? wp1 : wp2;
        int idx = (blk % 2304) * 256 + t;
        int j    = idx & 7;
        int lane = (idx >> 3) & 63;
        int ot   = (idx >> 9) & 15;
        int slab = idx >> 13;                        // 0..71
        int k = slab >> 3, cc = slab & 7;
        int o = ot * 16 + (lane & 15);
        int c = cc * 32 + (lane >> 4) * 8 + j;
        wp[idx] = f2bf(w[(size_t)(o * C_ + c) * KK_ + k]);
    } else if (blk < 4672) {
        int q = blk - 4608;                          // 0..63
        const float* pw = (q < 32) ? pw1 : pw2;
        short* ppk = (q < 32) ? ppk1 : ppk2;
        int idx = (q & 31) * 256 + t;                // 0..8191
        int j = idx & 7, lane = (idx >> 3) & 63;
        int ot = (idx >> 9) & 1, sl = idx >> 10;     // 0..7
        int o = ot * 16 + (lane & 15);
        int k = sl * 32 + (lane >> 4) * 8 + j;
        ppk[idx] = (o < NOFF_) ? f2bf(pw[o * C_ + k]) : (short)0;
    } else if (blk < 4800) {
        int q = blk - 4672;                          // 0..127 = (b,g)
        size_t base = (size_t)q * CPG_ * HW_;
        const float4* in4 = (const float4*)(x + base);
        float s = 0.f, ss = 0.f;
        for (int i = t; i < 8192; i += 256) {
            float4 v = in4[i];
            s  += v.x + v.y + v.z + v.w;
            ss += v.x * v.x + v.y * v.y + v.z * v.z + v.w * v.w;
        }
        #pragma unroll
        for (int d = 32; d > 0; d >>= 1) {
            s  += __shfl_down(s, d, 64);
            ss += __shfl_down(ss, d, 64);
        }
        __shared__ float red[8];
        int wid = t >> 6;
        if ((t & 63) == 0) { red[wid] = s; red[4 + wid] = ss; }
        __syncthreads();
        if (t == 0) {
            float S  = red[0] + red[1] + red[2] + red[3];
            float SS = red[4] + red[5] + red[6] + red[7];
            float m = S / 32768.f;
            float var = SS / 32768.f - m * m;
            stats1[q] = make_float2(m, rsqrtf(var + 1e-5f));
        }
    } else {
        if (t < 128) { gsum[t] = 0.f; gss[t] = 0.f; }
    }
}

// ---------------------------------------------------------------------------
// K1: fused GroupNorm-apply + ReLU + dual-layout write.
// Reads x (fp32, layer 1) or y1 (bf16, layer 2), applies per-channel affine
// from precomputed stats (stats1 or atomic raw sums), writes BOTH
// hbf bf16 [C][HW] (for dw7) and hbt bf16 [HW][C] (for the gather) via an
// LDS transpose tile. Block = (b, 64-px tile); grid 256.
// ---------------------------------------------------------------------------
__global__ __launch_bounds__(256) void gnt_kernel(
    const float* __restrict__ xin, const short* __restrict__ yin,
    const float2* __restrict__ stats1, const float* __restrict__ gsum,
    const float* __restrict__ gss, const float* __restrict__ gamma,
    const float* __restrict__ beta, short* __restrict__ hbf,
    short* __restrict__ hbt, int layer)
{
    int q = blockIdx.x;                  // 0..255
    int b = q >> 6;
    int px0 = (q & 63) * 64;
    __shared__ unsigned ltile[64 * 132];
    __shared__ float2 sst[32];
    int t = threadIdx.x;
    if (t < 32) {
        float m, rs;
        if (layer == 1) { float2 v = stats1[b * 32 + t]; m = v.x; rs = v.y; }
        else {
            float s = gsum[b * 32 + t], ss = gss[b * 32 + t];
            m = s / 32768.f;
            float var = ss / 32768.f - m * m;
            rs = rsqrtf(var + 1e-5f);
        }
        sst[t] = make_float2(m, rs);
    }
    __syncthreads();
    int pq4 = t & 15, cphi = t >> 4;
    #pragma unroll
    for (int i = 0; i < 8; ++i) {
        int cp = i * 16 + cphi;          // channel pair 0..127
        int c0 = 2 * cp, c1 = c0 + 1;
        float2 st = sst[c0 >> 3];
        float ga0 = gamma[c0] * st.y, be0 = beta[c0] - st.x * ga0;
        float ga1 = gamma[c1] * st.y, be1 = beta[c1] - st.x * ga1;
        short4v lo, hi;
        if (layer == 1) {
            const float* r0 = xin + (size_t)(b * C_ + c0) * HW_ + px0 + pq4 * 4;
            float4 v0 = *(const float4*)r0;
            float4 v1 = *(const float4*)(r0 + HW_);
            lo.x = f2bf(fmaxf(fmaf(v0.x, ga0, be0), 0.f));
            lo.y = f2bf(fmaxf(fmaf(v0.y, ga0, be0), 0.f));
            lo.z = f2bf(fmaxf(fmaf(v0.z, ga0, be0), 0.f));
            lo.w = f2bf(fmaxf(fmaf(v0.w, ga0, be0), 0.f));
            hi.x = f2bf(fmaxf(fmaf(v1.x, ga1, be1), 0.f));
            hi.y = f2bf(fmaxf(fmaf(v1.y, ga1, be1), 0.f));
            hi.z = f2bf(fmaxf(fmaf(v1.z, ga1, be1), 0.f));
            hi.w = f2bf(fmaxf(fmaf(v1.w, ga1, be1), 0.f));
        } else {
            const short* r0 = yin + (size_t)(b * C_ + c0) * HW_ + px0 + pq4 * 4;
            short4v v0 = *(const short4v*)r0;
            short4v v1 = *(const short4v*)(r0 + HW_);
            lo.x = f2bf(fmaxf(fmaf(bf2f(v0.x), ga0, be0), 0.f));
            lo.y = f2bf(fmaxf(fmaf(bf2f(v0.y), ga0, be0), 0.f));
            lo.z = f2bf(fmaxf(fmaf(bf2f(v0.z), ga0, be0), 0.f));
            lo.w = f2bf(fmaxf(fmaf(bf2f(v0.w), ga0, be0), 0.f));
            hi.x = f2bf(fmaxf(fmaf(bf2f(v1.x), ga1, be1), 0.f));
            hi.y = f2bf(fmaxf(fmaf(bf2f(v1.y), ga1, be1), 0.f));
            hi.z = f2bf(fmaxf(fmaf(bf2f(v1.z), ga1, be1), 0.f));
            hi.w = f2bf(fmaxf(fmaf(bf2f(v1.w), ga1, be1), 0.f));
        }
        *(short4v*)(hbf + (size_t)(b * C_ + c0) * HW_ + px0 + pq4 * 4) = lo;
        *(short4v*)(hbf + (size_t)(b * C_ + c1) * HW_ + px0 + pq4 * 4) = hi;
        #pragma unroll
        for (int j = 0; j < 4; ++j) {
            int pl = pq4 * 4 + j;
            unsigned wrd = (unsigned)(unsigned short)lo[j]
                         | ((unsigned)(unsigned short)hi[j] << 16);
            ltile[pl * 132 + (cp ^ ((pl & 7) << 2))] = wrd;
        }
    }
    __syncthreads();
    int co = t & 31, ph = t >> 5;
    #pragma unroll
    for (int r = 0; r < 8; ++r) {
        int pl = r * 8 + ph;
        uint4 v = *(const uint4*)&ltile[pl * 132 + ((co * 4) ^ ((pl & 7) << 2))];
        *(uint4*)(hbt + ((size_t)b * HW_ + px0 + pl) * C_ + co * 8) = v;
    }
}

// ---------------------------------------------------------------------------
// K2: depthwise 7x7 SAME conv, bf16 [C][HW] -> bf16 [C][HW].
// ---------------------------------------------------------------------------
__global__ __launch_bounds__(256) void dw7_kernel(
    const short* __restrict__ in, const float* __restrict__ dwk,
    short* __restrict__ out)
{
    int plane = blockIdx.x;
    int c = plane & (C_ - 1);
    const short* src = in + (size_t)plane * HW_;
    short* dst = out + (size_t)plane * HW_;
    __shared__ float tile[70 * 72];
    __shared__ float wk[49];
    int t = threadIdx.x;
    if (t < 49) wk[t] = dwk[c * 49 + t];
    for (int i = t; i < 70 * 72; i += 256) tile[i] = 0.f;
    __syncthreads();
    const short4v* src4 = (const short4v*)src;
    for (int i = t; i < HW_ / 4; i += 256) {
        short4v v = src4[i];
        int y = i >> 4, x = (i & 15) * 4;
        float* tp = &tile[(y + 3) * 72 + (x + 3)];
        tp[0] = bf2f(v.x); tp[1] = bf2f(v.y);
        tp[2] = bf2f(v.z); tp[3] = bf2f(v.w);
    }
    __syncthreads();
    #pragma unroll
    for (int it = 0; it < 4; ++it) {
        int idx = it * 256 + t;
        int y = idx >> 4;
        int x0 = (idx & 15) * 4;
        float a0 = 0.f, a1 = 0.f, a2 = 0.f, a3 = 0.f;
        #pragma unroll
        for (int dy = 0; dy < 7; ++dy) {
            const float* tr = &tile[(y + dy) * 72 + x0];
            float4 ra = *(const float4*)tr;
            float4 rb = *(const float4*)(tr + 4);
            float4 rc = *(const float4*)(tr + 8);
            float r[12] = {ra.x, ra.y, ra.z, ra.w,
                           rb.x, rb.y, rb.z, rb.w,
                           rc.x, rc.y, rc.z, rc.w};
            const float* wr = &wk[dy * 7];
            #pragma unroll
            for (int dx = 0; dx < 7; ++dx) {
                float wv = wr[dx];
                a0 = fmaf(r[dx], wv, a0);
                a1 = fmaf(r[dx + 1], wv, a1);
                a2 = fmaf(r[dx + 2], wv, a2);
                a3 = fmaf(r[dx + 3], wv, a3);
            }
        }
        short4v o;
        o.x = f2bf(a0); o.y = f2bf(a1); o.z = f2bf(a2); o.w = f2bf(a3);
        *(short4v*)&dst[y * 64 + x0] = o;
    }
}

// ---------------------------------------------------------------------------
// K3: fused {f-tile transpose + pw offsets (MFMA) + bilinear setup +
// deformable gather + MFMA einsum + epilogue (+gn2 stats atomics)}.
// Block = (b, row, px-half): grid 512, 1024 thr, ~41KB LDS -> 2 blocks/CU.
// ---------------------------------------------------------------------------
__global__ __launch_bounds__(1024) void deform_fused_kernel(
    const short* __restrict__ hbt,  const short* __restrict__ fdwc,
    const short* __restrict__ ppk,  const float* __restrict__ pwb,
    const short* __restrict__ wp,   const float* __restrict__ bias,
    const float* __restrict__ resid, float* __restrict__ outf,
    short* __restrict__ outb, float* __restrict__ gsum,
    float* __restrict__ gss)
{
    int blk = blockIdx.x;                // 512
    int b = blk >> 7;
    int row = (blk >> 1) & 63;
    int ph = blk & 1;                    // px half (0/1)
    __shared__ __align__(16) short sbuf[2][8192];   // 2 x 16KB (8 slabs x 32px)
    __shared__ int   pidx[288];
    __shared__ float cf[288][4];
    __shared__ float off_lds[NOFF_ * 32];
    int t = threadIdx.x;
    int wv = t >> 6, lane = t & 63;
    int pq = lane >> 4, pr = lane & 15;

    // ---- stage 0: f-tile [c][32px] into LDS (aliases sbuf[0]) ----
    short* ftile = &sbuf[0][0];
    {
        int c = t >> 2, seg = t & 3;
        const short* src = fdwc + (size_t)(b * C_ + c) * HW_
                         + row * 64 + ph * 32 + seg * 8;
        *(short8*)&ftile[c * 32 + seg * 8] = *(const short8*)src;
    }
    __syncthreads();

    // ---- stage A: pw offsets via MFMA (waves 0..3) ----
    if (wv < 4) {
        int ot = wv & 1, ptw = wv >> 1;
        int pxl = ptw * 16 + pr;
        const short8* ap = (const short8*)ppk;
        floatx4 pacc = (floatx4){0.f, 0.f, 0.f, 0.f};
        #pragma unroll
        for (int sl = 0; sl < 8; ++sl) {
            short8 bf;
            int cbase = sl * 32 + pq * 8;
            #pragma unroll
            for (int j = 0; j < 8; ++j) bf[j] = ftile[(cbase + j) * 32 + pxl];
            short8 af = ap[(sl * 2 + ot) * 64 + lane];
            pacc = __builtin_amdgcn_mfma_f32_16x16x32_bf16(af, bf, pacc, 0, 0, 0);
        }
        #pragma unroll
        for (int r = 0; r < 4; ++r) {
            int o = ot * 16 + pq * 4 + r;
            if (o < NOFF_) off_lds[o * 32 + pxl] = pacc[r] + pwb[o];
        }
    }
    __syncthreads();

    // ---- stage B: bilinear tables (288 = 9 taps x 32 px) ----
    if (t < 288) {
        int k = t >> 5, p = t & 31;
        float offy = off_lds[(2 * k) * 32 + p];
        float offx = off_lds[(2 * k + 1) * 32 + p];
        float py = (float)row + (float)(k / 3 - 1) + offy;
        float px = (float)(ph * 32 + p) + (float)(k % 3 - 1) + offx;
        float y0f = floorf(py), x0f = floorf(px);
        float wy1 = py - y0f, wx1 = px - x0f;
        float wy0 = 1.f - wy1, wx0 = 1.f - wx1;
        float y1f = y0f + 1.f, x1f = x0f + 1.f;
        bool vy0 = (y0f >= 0.f) && (y0f <= 63.f);
        bool vy1 = (y1f >= 0.f) && (y1f <= 63.f);
        bool vx0 = (x0f >= 0.f) && (x0f <= 63.f);
        bool vx1 = (x1f >= 0.f) && (x1f <= 63.f);
        int iy0 = (int)fminf(fmaxf(y0f, 0.f), 63.f);
        int iy1 = (int)fminf(fmaxf(y1f, 0.f), 63.f);
        int ix0 = (int)fminf(fmaxf(x0f, 0.f), 63.f);
        int ix1 = (int)fminf(fmaxf(x1f, 0.f), 63.f);
        pidx[t] = iy0 | (ix0 << 8) | (iy1 << 16) | (ix1 << 24);
        cf[t][0] = (vy0 && vx0) ? wy0 * wx0 : 0.f;
        cf[t][1] = (vy0 && vx1) ? wy0 * wx1 : 0.f;
        cf[t][2] = (vy1 && vx0) ? wy1 * wx0 : 0.f;
        cf[t][3] = (vy1 && vx1) ? wy1 * wx1 : 0.f;
    }
    __syncthreads();       // also ends ftile lifetime (sbuf reuse below)

    // ---- stage C: 9 groups (taps) x 8 slabs x 32px, double-buffered ----
    int sl = t >> 7;                     // slab 0..7
    int u = t & 127;
    int pxl = u >> 2, cb = u & 3;
    int u2 = pxl * 4 + (cb ^ ((pxl + (pxl >> 2)) & 3));
    const short* hb0 = hbt + ((size_t)b * HW_) * C_ + sl * 32 + cb * 8;

    short8 ra[4];
    auto prefetch = [&](int g) {
        int pk = pidx[g * 32 + pxl];
        int iy0 = pk & 255, ix0 = (pk >> 8) & 255;
        int iy1 = (pk >> 16) & 255, ix1 = (pk >> 24) & 255;
        ra[0] = *(const short8*)(hb0 + (size_t)(iy0 * 64 + ix0) * C_);
        ra[1] = *(const short8*)(hb0 + (size_t)(iy0 * 64 + ix1) * C_);
        ra[2] = *(const short8*)(hb0 + (size_t)(iy1 * 64 + ix0) * C_);
        ra[3] = *(const short8*)(hb0 + (size_t)(iy1 * 64 + ix1) * C_);
    };
    auto stage_write = [&](int g, int bi) {
        int e = g * 32 + pxl;
        float w00 = cf[e][0], w01 = cf[e][1], w10 = cf[e][2], w11 = cf[e][3];
        short8 v8;
        #pragma unroll
        for (int j = 0; j < 8; ++j) {
            v8[j] = f2bf(w00 * bf2f(ra[0][j]) + w01 * bf2f(ra[1][j])
                       + w10 * bf2f(ra[2][j]) + w11 * bf2f(ra[3][j]));
        }
        *(short8*)&sbuf[bi][sl * 1024 + u2 * 8] = v8;
    };

    floatx4 acc[2];
    acc[0] = (floatx4){0.f, 0.f, 0.f, 0.f};
    acc[1] = (floatx4){0.f, 0.f, 0.f, 0.f};
    int ub[2];
    #pragma unroll
    for (int pt = 0; pt < 2; ++pt) {
        int px2 = pt * 16 + pr;
        ub[pt] = px2 * 4 + (pq ^ ((px2 + (px2 >> 2)) & 3));
    }

    prefetch(0);
    stage_write(0, 0);
    prefetch(1);
    __syncthreads();

    const short8* wp8 = (const short8*)wp;
    for (int g = 0; g < 9; ++g) {
        const short* sb = sbuf[g & 1];
        #pragma unroll
        for (int half = 0; half < 2; ++half) {
            short8 af[4];
            #pragma unroll
            for (int q2 = 0; q2 < 4; ++q2)
                af[q2] = wp8[(size_t)((g * 8 + half * 4 + q2) * 16 + wv) * 64 + lane];
            #pragma unroll
            for (int q2 = 0; q2 < 4; ++q2) {
                int s2 = half * 4 + q2;
                #pragma unroll
                for (int pt = 0; pt < 2; ++pt) {
                    short8 bfv = *(const short8*)&sb[s2 * 1024 + ub[pt] * 8];
                    acc[pt] = __builtin_amdgcn_mfma_f32_16x16x32_bf16(
                        af[q2], bfv, acc[pt], 0, 0, 0);
                }
            }
        }
        if (g + 1 < 9) {
            stage_write(g + 1, (g + 1) & 1);
            if (g + 2 < 9) prefetch(g + 2);
        }
        __syncthreads();
    }

    // ---- epilogue (+ optional gn2 stats) ----
    float ssum = 0.f, ssq = 0.f;
    #pragma unroll
    for (int r = 0; r < 4; ++r) {
        int o = wv * 16 + pq * 4 + r;
        float bo = bias[o];
        size_t obase = ((size_t)(b * C_ + o)) * HW_ + row * 64 + ph * 32 + pr;
        #pragma unroll
        for (int pt = 0; pt < 2; ++pt) {
            float v = acc[pt][r] + bo;
            if (outf) {
                outf[obase + pt * 16] = v + resid[obase + pt * 16];
            } else {
                short sv = f2bf(v);
                outb[obase + pt * 16] = sv;
                float vq = bf2f(sv);
                ssum += vq; ssq += vq * vq;
            }
        }
    }
    if (outb) {
        #pragma unroll
        for (int d = 1; d < 32; d <<= 1) {
            ssum += __shfl_xor(ssum, d, 64);
            ssq  += __shfl_xor(ssq, d, 64);
        }
        if ((lane & 31) == 0) {
            int grp = wv * 2 + (pq >> 1);
            atomicAdd(&gsum[b * 32 + grp], ssum);
            atomicAdd(&gss[b * 32 + grp], ssq);
        }
    }
}

// ---------------------------------------------------------------------------
extern "C" void kernel_launch(void* const* d_in, const int* in_sizes, int n_in,
                              void* d_out, int out_size, void* d_ws, size_t ws_size,
                              hipStream_t stream)
{
    const float* x     = (const float*)d_in[0];
    const float* gn1_g = (const float*)d_in[1];
    const float* gn1_b = (const float*)d_in[2];
    const float* dw1   = (const float*)d_in[3];
    const float* pw1   = (const float*)d_in[4];
    const float* pwb1  = (const float*)d_in[5];
    const float* w1    = (const float*)d_in[6];
    const float* b1    = (const float*)d_in[7];
    const float* gn2_g = (const float*)d_in[8];
    const float* gn2_b = (const float*)d_in[9];
    const float* dw2   = (const float*)d_in[10];
    const float* pw2   = (const float*)d_in[11];
    const float* pwb2  = (const float*)d_in[12];
    const float* w2    = (const float*)d_in[13];
    const float* b2    = (const float*)d_in[14];
    float* out = (float*)d_out;

    float* ws   = (float*)d_ws;
    short* y1b    = (short*)ws;                  // bf16 [B][C][HW]  (8 MB)
    short* hbf    = (short*)(ws + 2097152);      // bf16 [B][C][HW]  (8 MB)
    short* hbt    = (short*)(ws + 4194304);      // bf16 [B][HW][C]  (8 MB)
    short* fdwc   = (short*)(ws + 6291456);      // bf16 [B][C][HW]  (8 MB)
    short* wp1    = (short*)(ws + 8388608);      // 589,824 bf16
    short* wp2    = (short*)(ws + 8683520);
    short* ppk1   = (short*)(ws + 8978432);      // 8,192 bf16
    short* ppk2   = (short*)(ws + 8982528);
    float2* st1   = (float2*)(ws + 8986624);     // 128 float2
    float* gsum   = ws + 8986880;                // 128
    float* gss    = ws + 8987008;                // 128

    prep_kernel<<<4801, 256, 0, stream>>>(w1, w2, pw1, pw2, x,
                                          wp1, wp2, ppk1, ppk2,
                                          st1, gsum, gss);

    // layer 1
    gnt_kernel<<<256, 256, 0, stream>>>(x, nullptr, st1, gsum, gss,
                                        gn1_g, gn1_b, hbf, hbt, 1);
    dw7_kernel<<<B_ * C_, 256, 0, stream>>>(hbf, dw1, fdwc);
    deform_fused_kernel<<<512, 1024, 0, stream>>>(
        hbt, fdwc, ppk1, pwb1, wp1, b1, nullptr, nullptr, y1b, gsum, gss);

    // layer 2 (+ residual x)
    gnt_kernel<<<256, 256, 0, stream>>>(nullptr, y1b, st1, gsum, gss,
                                        gn2_g, gn2_b, hbf, hbt, 2);
    dw7_kernel<<<B_ * C_, 256, 0, stream>>>(hbf, dw2, fdwc);
    deform_fused_kernel<<<512, 1024, 0, stream>>>(
        hbt, fdwc, ppk2, pwb2, wp2, b2, x, out, nullptr, nullptr, nullptr);
}

// Round 8
// 263.616 us; speedup vs baseline: 1.1620x; 1.1620x over previous
//
#include <hip/hip_runtime.h>

#define B_    4
#define C_    256
#define H_    64
#define W_    64
#define HW_   4096
#define NG_   32
#define CPG_  8
#define KK_   9
#define NOFF_ 18

typedef __attribute__((ext_vector_type(8))) short short8;
typedef __attribute__((ext_vector_type(4))) short short4v;
typedef __attribute__((ext_vector_type(4))) float floatx4;

static __device__ __forceinline__ short f2bf(float f) {
    union { float f; unsigned u; } v; v.f = f;
    unsigned r = v.u + 0x7fff + ((v.u >> 16) & 1);   // RNE
    return (short)(r >> 16);
}
static __device__ __forceinline__ float bf2f(short s) {
    union { unsigned u; float f; } v;
    v.u = ((unsigned)(unsigned short)s) << 16;
    return v.f;
}

// ---------------------------------------------------------------------------
// K0: prep — weight packs + gn1 stats + zero gn2-stats accumulators.
// ---------------------------------------------------------------------------
__global__ __launch_bounds__(256) void prep_kernel(
    const float* __restrict__ w1, const float* __restrict__ w2,
    const float* __restrict__ pw1, const float* __restrict__ pw2,
    const float* __restrict__ x,
    short* __restrict__ wp1, short* __restrict__ wp2,
    short* __restrict__ ppk1, short* __restrict__ ppk2,
    float2* __restrict__ stats1, float* __restrict__ gsum,
    float* __restrict__ gss)
{
    int blk = blockIdx.x;
    int t = threadIdx.x;
    if (blk < 4608) {
        const float* w = (blk < 2304) ? w1 : w2;
        short* wp = (blk < 2304) ? wp1 : wp2;
        int idx = (blk % 2304) * 256 + t;
        int j    = idx & 7;
        int lane = (idx >> 3) & 63;
        int ot   = (idx >> 9) & 15;
        int slab = idx >> 13;                        // 0..71
        int k = slab >> 3, cc = slab & 7;
        int o = ot * 16 + (lane & 15);
        int c = cc * 32 + (lane >> 4) * 8 + j;
        wp[idx] = f2bf(w[(size_t)(o * C_ + c) * KK_ + k]);
    } else if (blk < 4672) {
        int q = blk - 4608;                          // 0..63
        const float* pw = (q < 32) ? pw1 : pw2;
        short* ppk = (q < 32) ? ppk1 : ppk2;
        int idx = (q & 31) * 256 + t;                // 0..8191
        int j = idx & 7, lane = (idx >> 3) & 63;
        int ot = (idx >> 9) & 1, sl = idx >> 10;     // 0..7
        int o = ot * 16 + (lane & 15);
        int k = sl * 32 + (lane >> 4) * 8 + j;
        ppk[idx] = (o < NOFF_) ? f2bf(pw[o * C_ + k]) : (short)0;
    } else if (blk < 4800) {
        int q = blk - 4672;                          // 0..127 = (b,g)
        size_t base = (size_t)q * CPG_ * HW_;
        const float4* in4 = (const float4*)(x + base);
        float s = 0.f, ss = 0.f;
        for (int i = t; i < 8192; i += 256) {
            float4 v = in4[i];
            s  += v.x + v.y + v.z + v.w;
            ss += v.x * v.x + v.y * v.y + v.z * v.z + v.w * v.w;
        }
        #pragma unroll
        for (int d = 32; d > 0; d >>= 1) {
            s  += __shfl_down(s, d, 64);
            ss += __shfl_down(ss, d, 64);
        }
        __shared__ float red[8];
        int wid = t >> 6;
        if ((t & 63) == 0) { red[wid] = s; red[4 + wid] = ss; }
        __syncthreads();
        if (t == 0) {
            float S  = red[0] + red[1] + red[2] + red[3];
            float SS = red[4] + red[5] + red[6] + red[7];
            float m = S / 32768.f;
            float var = SS / 32768.f - m * m;
            stats1[q] = make_float2(m, rsqrtf(var + 1e-5f));
        }
    } else {
        if (t < 128) { gsum[t] = 0.f; gss[t] = 0.f; }
    }
}

// ---------------------------------------------------------------------------
// K1: fused GroupNorm-apply + ReLU + dual-layout write ([C][HW] + [HW][C]).
// ---------------------------------------------------------------------------
__global__ __launch_bounds__(256) void gnt_kernel(
    const float* __restrict__ xin, const short* __restrict__ yin,
    const float2* __restrict__ stats1, const float* __restrict__ gsum,
    const float* __restrict__ gss, const float* __restrict__ gamma,
    const float* __restrict__ beta, short* __restrict__ hbf,
    short* __restrict__ hbt, int layer)
{
    int q = blockIdx.x;                  // 0..255
    int b = q >> 6;
    int px0 = (q & 63) * 64;
    __shared__ unsigned ltile[64 * 132];
    __shared__ float2 sst[32];
    int t = threadIdx.x;
    if (t < 32) {
        float m, rs;
        if (layer == 1) { float2 v = stats1[b * 32 + t]; m = v.x; rs = v.y; }
        else {
            float s = gsum[b * 32 + t], ss = gss[b * 32 + t];
            m = s / 32768.f;
            float var = ss / 32768.f - m * m;
            rs = rsqrtf(var + 1e-5f);
        }
        sst[t] = make_float2(m, rs);
    }
    __syncthreads();
    int pq4 = t & 15, cphi = t >> 4;
    #pragma unroll
    for (int i = 0; i < 8; ++i) {
        int cp = i * 16 + cphi;          // channel pair 0..127
        int c0 = 2 * cp, c1 = c0 + 1;
        float2 st = sst[c0 >> 3];
        float ga0 = gamma[c0] * st.y, be0 = beta[c0] - st.x * ga0;
        float ga1 = gamma[c1] * st.y, be1 = beta[c1] - st.x * ga1;
        short4v lo, hi;
        if (layer == 1) {
            const float* r0 = xin + (size_t)(b * C_ + c0) * HW_ + px0 + pq4 * 4;
            float4 v0 = *(const float4*)r0;
            float4 v1 = *(const float4*)(r0 + HW_);
            lo.x = f2bf(fmaxf(fmaf(v0.x, ga0, be0), 0.f));
            lo.y = f2bf(fmaxf(fmaf(v0.y, ga0, be0), 0.f));
            lo.z = f2bf(fmaxf(fmaf(v0.z, ga0, be0), 0.f));
            lo.w = f2bf(fmaxf(fmaf(v0.w, ga0, be0), 0.f));
            hi.x = f2bf(fmaxf(fmaf(v1.x, ga1, be1), 0.f));
            hi.y = f2bf(fmaxf(fmaf(v1.y, ga1, be1), 0.f));
            hi.z = f2bf(fmaxf(fmaf(v1.z, ga1, be1), 0.f));
            hi.w = f2bf(fmaxf(fmaf(v1.w, ga1, be1), 0.f));
        } else {
            const short* r0 = yin + (size_t)(b * C_ + c0) * HW_ + px0 + pq4 * 4;
            short4v v0 = *(const short4v*)r0;
            short4v v1 = *(const short4v*)(r0 + HW_);
            lo.x = f2bf(fmaxf(fmaf(bf2f(v0.x), ga0, be0), 0.f));
            lo.y = f2bf(fmaxf(fmaf(bf2f(v0.y), ga0, be0), 0.f));
            lo.z = f2bf(fmaxf(fmaf(bf2f(v0.z), ga0, be0), 0.f));
            lo.w = f2bf(fmaxf(fmaf(bf2f(v0.w), ga0, be0), 0.f));
            hi.x = f2bf(fmaxf(fmaf(bf2f(v1.x), ga1, be1), 0.f));
            hi.y = f2bf(fmaxf(fmaf(bf2f(v1.y), ga1, be1), 0.f));
            hi.z = f2bf(fmaxf(fmaf(bf2f(v1.z), ga1, be1), 0.f));
            hi.w = f2bf(fmaxf(fmaf(bf2f(v1.w), ga1, be1), 0.f));
        }
        *(short4v*)(hbf + (size_t)(b * C_ + c0) * HW_ + px0 + pq4 * 4) = lo;
        *(short4v*)(hbf + (size_t)(b * C_ + c1) * HW_ + px0 + pq4 * 4) = hi;
        #pragma unroll
        for (int j = 0; j < 4; ++j) {
            int pl = pq4 * 4 + j;
            unsigned wrd = (unsigned)(unsigned short)lo[j]
                         | ((unsigned)(unsigned short)hi[j] << 16);
            ltile[pl * 132 + (cp ^ ((pl & 7) << 2))] = wrd;
        }
    }
    __syncthreads();
    int co = t & 31, ph = t >> 5;
    #pragma unroll
    for (int r = 0; r < 8; ++r) {
        int pl = r * 8 + ph;
        uint4 v = *(const uint4*)&ltile[pl * 132 + ((co * 4) ^ ((pl & 7) << 2))];
        *(uint4*)(hbt + ((size_t)b * HW_ + px0 + pl) * C_ + co * 8) = v;
    }
}

// ---------------------------------------------------------------------------
// K2: depthwise 7x7 SAME conv, bf16 [C][HW] -> bf16 [C][HW].
// ---------------------------------------------------------------------------
__global__ __launch_bounds__(256) void dw7_kernel(
    const short* __restrict__ in, const float* __restrict__ dwk,
    short* __restrict__ out)
{
    int plane = blockIdx.x;
    int c = plane & (C_ - 1);
    const short* src = in + (size_t)plane * HW_;
    short* dst = out + (size_t)plane * HW_;
    __shared__ float tile[70 * 72];
    __shared__ float wk[49];
    int t = threadIdx.x;
    if (t < 49) wk[t] = dwk[c * 49 + t];
    for (int i = t; i < 70 * 72; i += 256) tile[i] = 0.f;
    __syncthreads();
    const short4v* src4 = (const short4v*)src;
    for (int i = t; i < HW_ / 4; i += 256) {
        short4v v = src4[i];
        int y = i >> 4, x = (i & 15) * 4;
        float* tp = &tile[(y + 3) * 72 + (x + 3)];
        tp[0] = bf2f(v.x); tp[1] = bf2f(v.y);
        tp[2] = bf2f(v.z); tp[3] = bf2f(v.w);
    }
    __syncthreads();
    #pragma unroll
    for (int it = 0; it < 4; ++it) {
        int idx = it * 256 + t;
        int y = idx >> 4;
        int x0 = (idx & 15) * 4;
        float a0 = 0.f, a1 = 0.f, a2 = 0.f, a3 = 0.f;
        #pragma unroll
        for (int dy = 0; dy < 7; ++dy) {
            const float* tr = &tile[(y + dy) * 72 + x0];
            float4 ra = *(const float4*)tr;
            float4 rb = *(const float4*)(tr + 4);
            float4 rc = *(const float4*)(tr + 8);
            float r[12] = {ra.x, ra.y, ra.z, ra.w,
                           rb.x, rb.y, rb.z, rb.w,
                           rc.x, rc.y, rc.z, rc.w};
            const float* wr = &wk[dy * 7];
            #pragma unroll
            for (int dx = 0; dx < 7; ++dx) {
                float wv = wr[dx];
                a0 = fmaf(r[dx], wv, a0);
                a1 = fmaf(r[dx + 1], wv, a1);
                a2 = fmaf(r[dx + 2], wv, a2);
                a3 = fmaf(r[dx + 3], wv, a3);
            }
        }
        short4v o;
        o.x = f2bf(a0); o.y = f2bf(a1); o.z = f2bf(a2); o.w = f2bf(a3);
        *(short4v*)&dst[y * 64 + x0] = o;
    }
}

// ---------------------------------------------------------------------------
// K3: fused deform. R6 geometry (block = (b,row), 64px, 9 groups x 8 slabs,
// 2x32KB sbuf) + software pipeline: corner loads for g+2 issued at the TOP
// of group g into the ping-pong register set freed by group g's staging, so
// the vmcnt(0) drain at the barrier finds them complete.
// ---------------------------------------------------------------------------
__global__ __launch_bounds__(1024, 4) void deform_fused_kernel(
    const short* __restrict__ hbt,  const short* __restrict__ fdwc,
    const short* __restrict__ ppk,  const float* __restrict__ pwb,
    const short* __restrict__ wp,   const float* __restrict__ bias,
    const float* __restrict__ resid, float* __restrict__ outf,
    short* __restrict__ outb, float* __restrict__ gsum,
    float* __restrict__ gss)
{
    int b = blockIdx.x >> 6;
    int row = blockIdx.x & 63;
    __shared__ __align__(16) short sbuf[2][16384];   // 2 x 32KB
    __shared__ int   pidx[576];
    __shared__ float cf[576][4];
    __shared__ float off_lds[NOFF_ * 64];
    int t = threadIdx.x;
    int wv = t >> 6, lane = t & 63;
    int pq = lane >> 4, pr = lane & 15;

    // ---- stage 0: f-tile [256c][64px] into LDS (aliases sbuf[0]) ----
    short* ftile = &sbuf[0][0];
    {
        int c = t >> 2, seg = t & 3;
        const short* src = fdwc + (size_t)(b * C_ + c) * HW_ + row * 64;
        *(short8*)&ftile[c * 64 + seg * 8]       = *(const short8*)(src + seg * 8);
        *(short8*)&ftile[c * 64 + (seg + 4) * 8] = *(const short8*)(src + (seg + 4) * 8);
    }
    __syncthreads();

    // ---- stage A: pw offsets via MFMA (waves 0..7) ----
    if (wv < 8) {
        int ot = wv & 1, ptw = wv >> 1;
        int pxl = ptw * 16 + pr;
        const short8* ap = (const short8*)ppk;
        floatx4 pacc = (floatx4){0.f, 0.f, 0.f, 0.f};
        #pragma unroll
        for (int sl = 0; sl < 8; ++sl) {
            short8 bf;
            int cbase = sl * 32 + pq * 8;
            #pragma unroll
            for (int j = 0; j < 8; ++j) bf[j] = ftile[(cbase + j) * 64 + pxl];
            short8 af = ap[(sl * 2 + ot) * 64 + lane];
            pacc = __builtin_amdgcn_mfma_f32_16x16x32_bf16(af, bf, pacc, 0, 0, 0);
        }
        #pragma unroll
        for (int r = 0; r < 4; ++r) {
            int o = ot * 16 + pq * 4 + r;
            if (o < NOFF_) off_lds[o * 64 + pxl] = pacc[r] + pwb[o];
        }
    }
    __syncthreads();

    // ---- stage B: bilinear tables (576 = 9 taps x 64 px) ----
    if (t < 576) {
        int k = t >> 6, p = t & 63;
        float offy = off_lds[(2 * k) * 64 + p];
        float offx = off_lds[(2 * k + 1) * 64 + p];
        float py = (float)row + (float)(k / 3 - 1) + offy;
        float px = (float)p   + (float)(k % 3 - 1) + offx;
        float y0f = floorf(py), x0f = floorf(px);
        float wy1 = py - y0f, wx1 = px - x0f;
        float wy0 = 1.f - wy1, wx0 = 1.f - wx1;
        float y1f = y0f + 1.f, x1f = x0f + 1.f;
        bool vy0 = (y0f >= 0.f) && (y0f <= 63.f);
        bool vy1 = (y1f >= 0.f) && (y1f <= 63.f);
        bool vx0 = (x0f >= 0.f) && (x0f <= 63.f);
        bool vx1 = (x1f >= 0.f) && (x1f <= 63.f);
        int iy0 = (int)fminf(fmaxf(y0f, 0.f), 63.f);
        int iy1 = (int)fminf(fmaxf(y1f, 0.f), 63.f);
        int ix0 = (int)fminf(fmaxf(x0f, 0.f), 63.f);
        int ix1 = (int)fminf(fmaxf(x1f, 0.f), 63.f);
        pidx[t] = iy0 | (ix0 << 8) | (iy1 << 16) | (ix1 << 24);
        cf[t][0] = (vy0 && vx0) ? wy0 * wx0 : 0.f;
        cf[t][1] = (vy0 && vx1) ? wy0 * wx1 : 0.f;
        cf[t][2] = (vy1 && vx0) ? wy1 * wx0 : 0.f;
        cf[t][3] = (vy1 && vx1) ? wy1 * wx1 : 0.f;
    }
    __syncthreads();

    // ---- stage C: 9 groups (taps) x 8 slabs, ping-pong pipelined ----
    int ssl0 = t >> 8;                   // 0..3 (handles slabs ssl0, ssl0+4)
    int spx = (t >> 2) & 63, scb = t & 3;
    int u2 = spx * 4 + (scb ^ ((spx + (spx >> 2)) & 3));
    const short* hb0 = hbt + ((size_t)b * HW_) * C_ + ssl0 * 32 + scb * 8;
    const short* hb1 = hb0 + 128;        // slab ssl0+4

    short8 rs0[8], rs1[8];               // two corner register sets
    auto prefetch = [&](int g, short8* r) {
        int pk = pidx[g * 64 + spx];
        int iy0 = pk & 255, ix0 = (pk >> 8) & 255;
        int iy1 = (pk >> 16) & 255, ix1 = (pk >> 24) & 255;
        size_t a00 = (size_t)(iy0 * 64 + ix0) * C_;
        size_t a01 = (size_t)(iy0 * 64 + ix1) * C_;
        size_t a10 = (size_t)(iy1 * 64 + ix0) * C_;
        size_t a11 = (size_t)(iy1 * 64 + ix1) * C_;
        r[0] = *(const short8*)(hb0 + a00);
        r[1] = *(const short8*)(hb0 + a01);
        r[2] = *(const short8*)(hb0 + a10);
        r[3] = *(const short8*)(hb0 + a11);
        r[4] = *(const short8*)(hb1 + a00);
        r[5] = *(const short8*)(hb1 + a01);
        r[6] = *(const short8*)(hb1 + a10);
        r[7] = *(const short8*)(hb1 + a11);
    };
    auto stage_write = [&](int g, int bi, const short8* r) {
        int e = g * 64 + spx;
        float w00 = cf[e][0], w01 = cf[e][1], w10 = cf[e][2], w11 = cf[e][3];
        short8 va, vb;
        #pragma unroll
        for (int j = 0; j < 8; ++j) {
            va[j] = f2bf(w00 * bf2f(r[0][j]) + w01 * bf2f(r[1][j])
                       + w10 * bf2f(r[2][j]) + w11 * bf2f(r[3][j]));
            vb[j] = f2bf(w00 * bf2f(r[4][j]) + w01 * bf2f(r[5][j])
                       + w10 * bf2f(r[6][j]) + w11 * bf2f(r[7][j]));
        }
        *(short8*)&sbuf[bi][ssl0 * 2048 + u2 * 8] = va;
        *(short8*)&sbuf[bi][(ssl0 + 4) * 2048 + u2 * 8] = vb;
    };

    floatx4 acc[4];
    #pragma unroll
    for (int pt = 0; pt < 4; ++pt) acc[pt] = (floatx4){0.f, 0.f, 0.f, 0.f};
    int ub[4];
    #pragma unroll
    for (int pt = 0; pt < 4; ++pt) {
        int px2 = pt * 16 + pr;
        ub[pt] = px2 * 4 + (pq ^ ((px2 + (px2 >> 2)) & 3));
    }

    prefetch(0, rs0);
    stage_write(0, 0, rs0);              // rs0 free after this
    prefetch(1, rs1);                    // rs1 holds g=1
    __syncthreads();

    const short8* wp8 = (const short8*)wp;
    #pragma unroll
    for (int g = 0; g < 9; ++g) {
        // issue next-next gather EARLY: full group of compute hides it
        if (g + 2 < 9) prefetch(g + 2, (g & 1) ? rs1 : rs0);
        const short* sb = sbuf[g & 1];
        #pragma unroll
        for (int half = 0; half < 2; ++half) {
            short8 af[4];
            #pragma unroll
            for (int q2 = 0; q2 < 4; ++q2)
                af[q2] = wp8[(size_t)((g * 8 + half * 4 + q2) * 16 + wv) * 64 + lane];
            #pragma unroll
            for (int q2 = 0; q2 < 4; ++q2) {
                int s2 = half * 4 + q2;
                #pragma unroll
                for (int pt = 0; pt < 4; ++pt) {
                    short8 bfv = *(const short8*)&sb[s2 * 2048 + ub[pt] * 8];
                    acc[pt] = __builtin_amdgcn_mfma_f32_16x16x32_bf16(
                        af[q2], bfv, acc[pt], 0, 0, 0);
                }
            }
        }
        if (g + 1 < 9)
            stage_write(g + 1, (g + 1) & 1, (g & 1) ? rs0 : rs1);
        __syncthreads();
    }

    // ---- epilogue (+ gn2 stats when writing bf16) ----
    float ssum = 0.f, ssq = 0.f;
    #pragma unroll
    for (int r = 0; r < 4; ++r) {
        int o = wv * 16 + pq * 4 + r;
        float bo = bias[o];
        size_t obase = ((size_t)(b * C_ + o)) * HW_ + row * 64 + pr;
        #pragma unroll
        for (int pt = 0; pt < 4; ++pt) {
            float v = acc[pt][r] + bo;
            if (outf) {
                outf[obase + pt * 16] = v + resid[obase + pt * 16];
            } else {
                short sv = f2bf(v);
                outb[obase + pt * 16] = sv;
                float vq = bf2f(sv);
                ssum += vq; ssq += vq * vq;
            }
        }
    }
    if (outb) {
        #pragma unroll
        for (int d = 1; d < 32; d <<= 1) {
            ssum += __shfl_xor(ssum, d, 64);
            ssq  += __shfl_xor(ssq, d, 64);
        }
        if ((lane & 31) == 0) {
            int grp = wv * 2 + (pq >> 1);
            atomicAdd(&gsum[b * 32 + grp], ssum);
            atomicAdd(&gss[b * 32 + grp], ssq);
        }
    }
}

// ---------------------------------------------------------------------------
extern "C" void kernel_launch(void* const* d_in, const int* in_sizes, int n_in,
                              void* d_out, int out_size, void* d_ws, size_t ws_size,
                              hipStream_t stream)
{
    const float* x     = (const float*)d_in[0];
    const float* gn1_g = (const float*)d_in[1];
    const float* gn1_b = (const float*)d_in[2];
    const float* dw1   = (const float*)d_in[3];
    const float* pw1   = (const float*)d_in[4];
    const float* pwb1  = (const float*)d_in[5];
    const float* w1    = (const float*)d_in[6];
    const float* b1    = (const float*)d_in[7];
    const float* gn2_g = (const float*)d_in[8];
    const float* gn2_b = (const float*)d_in[9];
    const float* dw2   = (const float*)d_in[10];
    const float* pw2   = (const float*)d_in[11];
    const float* pwb2  = (const float*)d_in[12];
    const float* w2    = (const float*)d_in[13];
    const float* b2    = (const float*)d_in[14];
    float* out = (float*)d_out;

    float* ws   = (float*)d_ws;
    short* y1b    = (short*)ws;                  // bf16 [B][C][HW]  (8 MB)
    short* hbf    = (short*)(ws + 2097152);      // bf16 [B][C][HW]  (8 MB)
    short* hbt    = (short*)(ws + 4194304);      // bf16 [B][HW][C]  (8 MB)
    short* fdwc   = (short*)(ws + 6291456);      // bf16 [B][C][HW]  (8 MB)
    short* wp1    = (short*)(ws + 8388608);      // 589,824 bf16
    short* wp2    = (short*)(ws + 8683520);
    short* ppk1   = (short*)(ws + 8978432);      // 8,192 bf16
    short* ppk2   = (short*)(ws + 8982528);
    float2* st1   = (float2*)(ws + 8986624);     // 128 float2
    float* gsum   = ws + 8986880;                // 128
    float* gss    = ws + 8987008;                // 128

    prep_kernel<<<4801, 256, 0, stream>>>(w1, w2, pw1, pw2, x,
                                          wp1, wp2, ppk1, ppk2,
                                          st1, gsum, gss);

    // layer 1
    gnt_kernel<<<256, 256, 0, stream>>>(x, nullptr, st1, gsum, gss,
                                        gn1_g, gn1_b, hbf, hbt, 1);
    dw7_kernel<<<B_ * C_, 256, 0, stream>>>(hbf, dw1, fdwc);
    deform_fused_kernel<<<B_ * H_, 1024, 0, stream>>>(
        hbt, fdwc, ppk1, pwb1, wp1, b1, nullptr, nullptr, y1b, gsum, gss);

    // layer 2 (+ residual x)
    gnt_kernel<<<256, 256, 0, stream>>>(nullptr, y1b, st1, gsum, gss,
                                        gn2_g, gn2_b, hbf, hbt, 2);
    dw7_kernel<<<B_ * C_, 256, 0, stream>>>(hbf, dw2, fdwc);
    deform_fused_kernel<<<B_ * H_, 1024, 0, stream>>>(
        hbt, fdwc, ppk2, pwb2, wp2, b2, x, out, nullptr, nullptr, nullptr);
}